// Round 8
// baseline (339.356 us; speedup 1.0000x reference)
//
#include <hip/hip_runtime.h>

#define N_NODES 50000
#define N_PAD   50048                            // 782 * 64
#define N_EDGES 1600000
#define HD 128                                   // H*D = 8*16
#define CHUNK 4096
#define NCHUNK ((N_EDGES + CHUNK - 1) / CHUNK)   // 391
#define NBUCKET ((N_NODES + 127) / 128)          // 391 buckets of 128 nodes

typedef __attribute__((ext_vector_type(8))) short short8;   // 8 bf16
typedef __attribute__((ext_vector_type(4))) float floatx4;

union U4S8 { uint4 u; short8 s; };

// round-to-nearest-even float -> bf16 bits
__device__ __forceinline__ unsigned short f2bf(float f) {
    unsigned u = __float_as_uint(f);
    unsigned r = (u + 0x7fffu + ((u >> 16) & 1u)) >> 16;
    return (unsigned short)r;
}

// ================= chunkhist + W-prep (fused grid) ==========================
__global__ __launch_bounds__(256) void k_chunkhist(
    const int* __restrict__ dst, int* __restrict__ chunkhist, int* __restrict__ btot,
    const float* __restrict__ WQ, const float* __restrict__ WK, const float* __restrict__ WV,
    unsigned short* __restrict__ Wf) {
    int t = threadIdx.x, c = blockIdx.x;
    if (c >= NCHUNK) {
        int tid = (c - NCHUNK) * 256 + t;        // 0..6143
        int lane = tid & 63;
        int kstep = (tid >> 6) & 3;
        int ntile = tid >> 8;
        int g = ntile >> 3;
        int col = (ntile & 7) * 16 + (lane & 15);
        int k0 = kstep * 32 + (lane >> 4) * 8;
        const float* W = (g == 0) ? WQ : (g == 1) ? WK : WV;
        unsigned short r[8];
#pragma unroll
        for (int j = 0; j < 8; ++j)
            r[j] = f2bf(W[(size_t)(k0 + j) * HD + col]);
        *(uint4*)(Wf + (size_t)tid * 8) = *(uint4*)r;
        return;
    }
    __shared__ int hist[NBUCKET];
    for (int i = t; i < NBUCKET; i += 256) hist[i] = 0;
    __syncthreads();
    int e0 = c * CHUNK;
    int cnt = min(CHUNK, N_EDGES - e0);
    const uint4* d4 = (const uint4*)(dst + e0);
    int cnt4 = cnt >> 2;
    for (int i = t; i < cnt4; i += 256) {
        uint4 v = d4[i];
        atomicAdd(&hist[v.x >> 7], 1);
        atomicAdd(&hist[v.y >> 7], 1);
        atomicAdd(&hist[v.z >> 7], 1);
        atomicAdd(&hist[v.w >> 7], 1);
    }
    __syncthreads();
    for (int i = t; i < NBUCKET; i += 256) {
        int v = hist[i];
        chunkhist[c * NBUCKET + i] = v;
        if (v) atomicAdd(&btot[i], v);           // fire-and-forget
    }
}

// per-(chunk,bucket) offsets; bucket base computed in-block (fused scan)
__global__ __launch_bounds__(256) void k_choff(const int* __restrict__ chunkhist,
                                               const int* __restrict__ btot,
                                               int* __restrict__ bucket_ptr,
                                               int* __restrict__ chunkoff) {
    int b = blockIdx.x, t = threadIdx.x;
    int x = 0;
    for (int i = t; i < NBUCKET; i += 256)
        if (i < b) x += btot[i];
    __shared__ int red[256];
    red[t] = x;
    __syncthreads();
    for (int off = 128; off > 0; off >>= 1) {
        if (t < off) red[t] += red[t + off];
        __syncthreads();
    }
    int base = red[0];
    if (t == 0) {
        bucket_ptr[b] = base;
        if (b == NBUCKET - 1) bucket_ptr[NBUCKET] = base + btot[b];
    }
    const int PER = (NCHUNK + 255) / 256;        // 2
    int c0 = t * PER;
    int v[PER];
    int s = 0;
#pragma unroll
    for (int i = 0; i < PER; ++i) {
        int c = c0 + i;
        v[i] = (c < NCHUNK) ? chunkhist[c * NBUCKET + b] : 0;
        s += v[i];
    }
    __shared__ int part[256];
    part[t] = s;
    __syncthreads();
    for (int off = 1; off < 256; off <<= 1) {
        int y = (t >= off) ? part[t - off] : 0;
        __syncthreads();
        part[t] += y;
        __syncthreads();
    }
    int run = base + part[t] - s;
#pragma unroll
    for (int i = 0; i < PER; ++i) {
        int c = c0 + i;
        if (c < NCHUNK) { chunkoff[c * NBUCKET + b] = run; run += v[i]; }
    }
}

__global__ __launch_bounds__(256) void k_scatter(const int* __restrict__ src,
                                                 const int* __restrict__ dst,
                                                 const int* __restrict__ chunkoff,
                                                 int* __restrict__ packed) {
    __shared__ int cur[NBUCKET];
    int t = threadIdx.x, c = blockIdx.x;
    for (int i = t; i < NBUCKET; i += 256) cur[i] = chunkoff[c * NBUCKET + i];
    __syncthreads();
    int e0 = c * CHUNK;
    int cnt = min(CHUNK, N_EDGES - e0);
    const uint4* d4 = (const uint4*)(dst + e0);
    const uint4* s4 = (const uint4*)(src + e0);
    int cnt4 = cnt >> 2;
    for (int i = t; i < cnt4; i += 256) {
        uint4 d = d4[i];
        uint4 s = s4[i];
        int pos;
        pos = atomicAdd(&cur[d.x >> 7], 1); packed[pos] = (s.x << 7) | (d.x & 127);
        pos = atomicAdd(&cur[d.y >> 7], 1); packed[pos] = (s.y << 7) | (d.y & 127);
        pos = atomicAdd(&cur[d.z >> 7], 1); packed[pos] = (s.z << 7) | (d.z & 127);
        pos = atomicAdd(&cur[d.w >> 7], 1); packed[pos] = (s.w << 7) | (d.w & 127);
    }
}

__global__ __launch_bounds__(256) void k_finalize(const int* __restrict__ bucket_ptr,
                                                  const int* __restrict__ packed,
                                                  int* __restrict__ row_ptr,
                                                  int* __restrict__ col_src) {
    __shared__ int hist[128], part[128], cur[128];
    int b = blockIdx.x, t = threadIdx.x;
    if (t < 128) hist[t] = 0;
    __syncthreads();
    int ebeg = bucket_ptr[b], eend = bucket_ptr[b + 1];
    int m = eend - ebeg;
    for (int i = t; i < m; i += 256)
        atomicAdd(&hist[packed[ebeg + i] & 127], 1);
    __syncthreads();
    int v = 0;
    if (t < 128) { v = hist[t]; part[t] = v; }
    __syncthreads();
    for (int off = 1; off < 128; off <<= 1) {
        int x = 0;
        if (t < 128 && t >= off) x = part[t - off];
        __syncthreads();
        if (t < 128) part[t] += x;
        __syncthreads();
    }
    if (t < 128) {
        int excl = part[t] - v;
        int node = b * 128 + t;
        if (node < N_NODES) row_ptr[node] = ebeg + excl;
        if (node == N_NODES - 1) row_ptr[N_NODES] = eend;
        cur[t] = ebeg + excl;
    }
    __syncthreads();
    for (int i = t; i < m; i += 256) {
        int p = packed[ebeg + i];
        int pos = atomicAdd(&cur[p & 127], 1);
        col_src[pos] = p >> 7;
    }
}

// ================= proj: bf16 MFMA GEMM, head-major epilogue ================
// Qh[head][node][16] fp32; KV[head][node][32] bf16 (K dims 0-15, V dims 16-31).

__global__ __launch_bounds__(256) void proj_mfma(
    const float* __restrict__ h, const unsigned short* __restrict__ Wf,
    const float* __restrict__ bQ, const float* __restrict__ bK, const float* __restrict__ bV,
    float* __restrict__ Qh, unsigned short* __restrict__ KV) {
    int t = threadIdx.x;
    int w = t >> 6;          // wave 0..3
    int l = t & 63;          // lane
    int row0 = blockIdx.x * 64 + w * 16;
    int arow = row0 + (l & 15);
    int akoff = (l >> 4) * 8;
    bool rowok = arow < N_NODES;

    short8 a[4];
#pragma unroll
    for (int ks = 0; ks < 4; ++ks) {
        unsigned short r[8];
        if (rowok) {
            const float4* ap = (const float4*)(h + (size_t)arow * HD + ks * 32 + akoff);
            float4 f0 = ap[0], f1 = ap[1];
            r[0] = f2bf(f0.x); r[1] = f2bf(f0.y); r[2] = f2bf(f0.z); r[3] = f2bf(f0.w);
            r[4] = f2bf(f1.x); r[5] = f2bf(f1.y); r[6] = f2bf(f1.z); r[7] = f2bf(f1.w);
        } else {
#pragma unroll
            for (int j = 0; j < 8; ++j) r[j] = 0;
        }
        a[ks] = *(short8*)r;
    }

    int orow0 = row0 + (l >> 4) * 4;   // output rows orow0..orow0+3
#pragma unroll
    for (int nt = 0; nt < 24; ++nt) {
        floatx4 acc = (floatx4){0.f, 0.f, 0.f, 0.f};
#pragma unroll
        for (int ks = 0; ks < 4; ++ks) {
            U4S8 u;
            u.u = *(const uint4*)(Wf + ((size_t)(nt * 4 + ks) * 64 + l) * 8);
            acc = __builtin_amdgcn_mfma_f32_16x16x32_bf16(a[ks], u.s, acc, 0, 0, 0);
        }
        int g = nt >> 3;
        int head = nt & 7;
        int ci = l & 15;
        float bias = (g == 0) ? bQ[head * 16 + ci] : (g == 1) ? bK[head * 16 + ci] : bV[head * 16 + ci];
#pragma unroll
        for (int r = 0; r < 4; ++r) {
            int grow = orow0 + r;
            if (grow < N_NODES) {
                float val = acc[r] + bias;
                size_t node_off = (size_t)head * N_PAD + grow;
                if (g == 0)      Qh[node_off * 16 + ci] = val;
                else if (g == 1) KV[node_off * 32 + ci] = f2bf(val);
                else             KV[node_off * 32 + 16 + ci] = f2bf(val);
            }
        }
    }
}

// ================= attention: head-split, XCD-pinned ========================
// blockIdx = grp*8 + head  (blockIdx%8 == head -> one head per XCD under
// round-robin dispatch; per-XCD KV working set 3.2 MB = L2-resident).
// Block 256 = 4 waves = 4 nodes, same head. Wave: 16 edge-slots x 4 lanes.
// Lane j (=l&3) holds KV row bytes j*16: j0=K0-7, j1=K8-15, j2=V0-7, j3=V8-15.

__device__ __forceinline__ float blo(unsigned u) { return __uint_as_float(u << 16); }
__device__ __forceinline__ float bhi(unsigned u) { return __uint_as_float(u & 0xffff0000u); }

__global__ __launch_bounds__(256) void attn_kernel(
    const float* __restrict__ Qh, const unsigned short* __restrict__ KV,
    const int* __restrict__ row_ptr, const int* __restrict__ col_src,
    float* __restrict__ out) {
    int head = blockIdx.x & 7;
    int grp  = blockIdx.x >> 3;
    int w = threadIdx.x >> 6;
    int n = grp * 4 + w;                 // 12500*4 = 50000 exactly
    int l = threadIdx.x & 63;
    int s = l >> 2;                      // edge slot 0..15
    int j = l & 3;                       // quarter-row piece

    // lane's 8 Q values: j0/j2 -> dims 0-7, j1/j3 -> dims 8-15
    const float4* qp = (const float4*)(Qh + ((size_t)head * N_PAD + n) * 16 + (j & 1) * 8);
    float4 qa = qp[0], qb = qp[1];

    float acc[8];
#pragma unroll
    for (int k = 0; k < 8; ++k) acc[k] = 0.f;
    float z = 0.f;

    int beg = row_ptr[n], end = row_ptr[n + 1];
    const unsigned short* KVh = KV + (size_t)head * N_PAD * 32;

    for (int base = beg; base < end; base += 64) {
        int mm = min(64, end - base);
        int e_l = col_src[(base + l < end) ? (base + l) : beg];
        int steps = (mm + 15) >> 4;

        int s0 = __shfl(e_l, s);
        uint4 kv = *(const uint4*)(KVh + (size_t)s0 * 32 + j * 8);

        for (int i = 0; i < steps; ++i) {
            uint4 nkv = kv;
            if (i + 1 < steps) {
                int s1 = __shfl(e_l, 16 * (i + 1) + s);
                nkv = *(const uint4*)(KVh + (size_t)s1 * 32 + j * 8);
            }
            // unpack own 8 values
            float v0 = blo(kv.x), v1 = bhi(kv.x), v2 = blo(kv.y), v3 = bhi(kv.y);
            float v4 = blo(kv.z), v5 = bhi(kv.z), v6 = blo(kv.w), v7 = bhi(kv.w);
            // partial dot (real for j0/j1, junk for j2/j3)
            float d = v0 * qa.x + v1 * qa.y + v2 * qa.z + v3 * qa.w
                    + v4 * qb.x + v5 * qb.y + v6 * qb.z + v7 * qb.w;
            d += __shfl_xor(d, 1);               // j0+j1 full K dot (j2+j3 junk)
            float dd = __shfl_xor(d, 2);         // bring K dot to j2/j3
            float kd = (l & 2) ? dd : d;
            float sc = __expf(fminf(fmaxf(kd * 0.25f, -5.f), 5.f));
            if (16 * i + s >= mm) sc = 0.f;
            // accumulate sc * own values (meaningful only in j2/j3)
            acc[0] = fmaf(sc, v0, acc[0]);
            acc[1] = fmaf(sc, v1, acc[1]);
            acc[2] = fmaf(sc, v2, acc[2]);
            acc[3] = fmaf(sc, v3, acc[3]);
            acc[4] = fmaf(sc, v4, acc[4]);
            acc[5] = fmaf(sc, v5, acc[5]);
            acc[6] = fmaf(sc, v6, acc[6]);
            acc[7] = fmaf(sc, v7, acc[7]);
            z += sc;
            kv = nkv;
        }
    }

    // reduce across 16 edge-slots (same j class): xor 4,8,16,32
#pragma unroll
    for (int k = 0; k < 8; ++k) {
        acc[k] += __shfl_xor(acc[k], 4);
        acc[k] += __shfl_xor(acc[k], 8);
        acc[k] += __shfl_xor(acc[k], 16);
        acc[k] += __shfl_xor(acc[k], 32);
    }
    z += __shfl_xor(z, 4);
    z += __shfl_xor(z, 8);
    z += __shfl_xor(z, 16);
    z += __shfl_xor(z, 32);

    if (s == 0 && (l & 2)) {             // lanes j=2 (dims 0-7), j=3 (dims 8-15)
        float inv = 1.f / z;
        float* O = out + (size_t)n * HD + head * 16 + (j & 1) * 8;
        ((float4*)O)[0] = (float4){acc[0] * inv, acc[1] * inv, acc[2] * inv, acc[3] * inv};
        ((float4*)O)[1] = (float4){acc[4] * inv, acc[5] * inv, acc[6] * inv, acc[7] * inv};
    }
}

// ================= launch ===================================================

static inline char* align256(char* p) {
    return (char*)(((uintptr_t)p + 255) & ~(uintptr_t)255);
}

extern "C" void kernel_launch(void* const* d_in, const int* in_sizes, int n_in,
                              void* d_out, int out_size, void* d_ws, size_t ws_size,
                              hipStream_t stream) {
    const float* h  = (const float*)d_in[0];
    const int*   src = (const int*)d_in[1];
    const int*   dst = (const int*)d_in[2];
    const float* WQ = (const float*)d_in[3];
    const float* WK = (const float*)d_in[4];
    const float* WV = (const float*)d_in[5];
    const float* bQ = (const float*)d_in[6];
    const float* bK = (const float*)d_in[7];
    const float* bV = (const float*)d_in[8];
    float* out = (float*)d_out;

    char* p = (char*)d_ws;
    float* Qh = (float*)p;                   p += (size_t)8 * N_PAD * 16 * 4;
    unsigned short* KV = (unsigned short*)p; p += (size_t)8 * N_PAD * 32 * 2;
    unsigned short* Wf = (unsigned short*)p; p += (size_t)24 * 4 * 64 * 8 * 2;
    p = align256(p);
    int* row_ptr    = (int*)p;               p += (N_NODES + 2) * 4;
    p = align256(p);
    int* bucket_ptr = (int*)p;               p += (NBUCKET + 1) * 4;
    p = align256(p);
    int* btot       = (int*)p;               p += NBUCKET * 4;
    p = align256(p);
    int* chunkhist  = (int*)p;               p += (size_t)NCHUNK * NBUCKET * 4;
    p = align256(p);
    int* chunkoff   = (int*)p;               p += (size_t)NCHUNK * NBUCKET * 4;
    p = align256(p);
    int* packed     = (int*)p;               p += (size_t)N_EDGES * 4;
    p = align256(p);
    int* col_src    = (int*)p;               p += (size_t)N_EDGES * 4;

    (void)hipMemsetAsync(btot, 0, NBUCKET * sizeof(int), stream);
    k_chunkhist<<<NCHUNK + 24, 256, 0, stream>>>(dst, chunkhist, btot, WQ, WK, WV, Wf);
    k_choff<<<NBUCKET, 256, 0, stream>>>(chunkhist, btot, bucket_ptr, chunkoff);
    k_scatter<<<NCHUNK, 256, 0, stream>>>(src, dst, chunkoff, packed);
    k_finalize<<<NBUCKET, 256, 0, stream>>>(bucket_ptr, packed, row_ptr, col_src);
    proj_mfma<<<N_PAD / 64, 256, 0, stream>>>(h, Wf, bQ, bK, bV, Qh, KV);
    attn_kernel<<<(N_NODES / 4) * 8, 256, 0, stream>>>(Qh, KV, row_ptr, col_src, out);
}

// Round 9
// 272.244 us; speedup vs baseline: 1.2465x; 1.2465x over previous
//
#include <hip/hip_runtime.h>

#define N_NODES 50000
#define N_PAD   50048                            // 782 * 64
#define N_EDGES 1600000
#define HD 128                                   // H*D = 8*16
#define CHUNK 4096
#define NCHUNK ((N_EDGES + CHUNK - 1) / CHUNK)   // 391
#define NBUCKET ((N_NODES + 127) / 128)          // 391 buckets of 128 nodes

typedef __attribute__((ext_vector_type(8))) short short8;   // 8 bf16
typedef __attribute__((ext_vector_type(4))) float floatx4;

union U4S8 { uint4 u; short8 s; };

// round-to-nearest-even float -> bf16 bits
__device__ __forceinline__ unsigned short f2bf(float f) {
    unsigned u = __float_as_uint(f);
    unsigned r = (u + 0x7fffu + ((u >> 16) & 1u)) >> 16;
    return (unsigned short)r;
}

// ================= chunkhist + W-prep (fused grid) ==========================
__global__ __launch_bounds__(256) void k_chunkhist(
    const int* __restrict__ dst, int* __restrict__ chunkhist, int* __restrict__ btot,
    const float* __restrict__ WQ, const float* __restrict__ WK, const float* __restrict__ WV,
    unsigned short* __restrict__ Wf) {
    int t = threadIdx.x, c = blockIdx.x;
    if (c >= NCHUNK) {
        int tid = (c - NCHUNK) * 256 + t;        // 0..6143
        int lane = tid & 63;
        int kstep = (tid >> 6) & 3;
        int ntile = tid >> 8;
        int g = ntile >> 3;
        int col = (ntile & 7) * 16 + (lane & 15);
        int k0 = kstep * 32 + (lane >> 4) * 8;
        const float* W = (g == 0) ? WQ : (g == 1) ? WK : WV;
        unsigned short r[8];
#pragma unroll
        for (int j = 0; j < 8; ++j)
            r[j] = f2bf(W[(size_t)(k0 + j) * HD + col]);
        *(uint4*)(Wf + (size_t)tid * 8) = *(uint4*)r;
        return;
    }
    __shared__ int hist[NBUCKET];
    for (int i = t; i < NBUCKET; i += 256) hist[i] = 0;
    __syncthreads();
    int e0 = c * CHUNK;
    int cnt = min(CHUNK, N_EDGES - e0);
    const uint4* d4 = (const uint4*)(dst + e0);
    int cnt4 = cnt >> 2;
    for (int i = t; i < cnt4; i += 256) {
        uint4 v = d4[i];
        atomicAdd(&hist[v.x >> 7], 1);
        atomicAdd(&hist[v.y >> 7], 1);
        atomicAdd(&hist[v.z >> 7], 1);
        atomicAdd(&hist[v.w >> 7], 1);
    }
    __syncthreads();
    for (int i = t; i < NBUCKET; i += 256) {
        int v = hist[i];
        chunkhist[c * NBUCKET + i] = v;
        if (v) atomicAdd(&btot[i], v);           // fire-and-forget
    }
}

// per-(chunk,bucket) offsets; bucket base computed in-block (fused scan)
__global__ __launch_bounds__(256) void k_choff(const int* __restrict__ chunkhist,
                                               const int* __restrict__ btot,
                                               int* __restrict__ bucket_ptr,
                                               int* __restrict__ chunkoff) {
    int b = blockIdx.x, t = threadIdx.x;
    int x = 0;
    for (int i = t; i < NBUCKET; i += 256)
        if (i < b) x += btot[i];
    __shared__ int red[256];
    red[t] = x;
    __syncthreads();
    for (int off = 128; off > 0; off >>= 1) {
        if (t < off) red[t] += red[t + off];
        __syncthreads();
    }
    int base = red[0];
    if (t == 0) {
        bucket_ptr[b] = base;
        if (b == NBUCKET - 1) bucket_ptr[NBUCKET] = base + btot[b];
    }
    const int PER = (NCHUNK + 255) / 256;        // 2
    int c0 = t * PER;
    int v[PER];
    int s = 0;
#pragma unroll
    for (int i = 0; i < PER; ++i) {
        int c = c0 + i;
        v[i] = (c < NCHUNK) ? chunkhist[c * NBUCKET + b] : 0;
        s += v[i];
    }
    __shared__ int part[256];
    part[t] = s;
    __syncthreads();
    for (int off = 1; off < 256; off <<= 1) {
        int y = (t >= off) ? part[t - off] : 0;
        __syncthreads();
        part[t] += y;
        __syncthreads();
    }
    int run = base + part[t] - s;
#pragma unroll
    for (int i = 0; i < PER; ++i) {
        int c = c0 + i;
        if (c < NCHUNK) { chunkoff[c * NBUCKET + b] = run; run += v[i]; }
    }
}

__global__ __launch_bounds__(256) void k_scatter(const int* __restrict__ src,
                                                 const int* __restrict__ dst,
                                                 const int* __restrict__ chunkoff,
                                                 int* __restrict__ packed) {
    __shared__ int cur[NBUCKET];
    int t = threadIdx.x, c = blockIdx.x;
    for (int i = t; i < NBUCKET; i += 256) cur[i] = chunkoff[c * NBUCKET + i];
    __syncthreads();
    int e0 = c * CHUNK;
    int cnt = min(CHUNK, N_EDGES - e0);
    const uint4* d4 = (const uint4*)(dst + e0);
    const uint4* s4 = (const uint4*)(src + e0);
    int cnt4 = cnt >> 2;
    for (int i = t; i < cnt4; i += 256) {
        uint4 d = d4[i];
        uint4 s = s4[i];
        int pos;
        pos = atomicAdd(&cur[d.x >> 7], 1); packed[pos] = (s.x << 7) | (d.x & 127);
        pos = atomicAdd(&cur[d.y >> 7], 1); packed[pos] = (s.y << 7) | (d.y & 127);
        pos = atomicAdd(&cur[d.z >> 7], 1); packed[pos] = (s.z << 7) | (d.z & 127);
        pos = atomicAdd(&cur[d.w >> 7], 1); packed[pos] = (s.w << 7) | (d.w & 127);
    }
}

__global__ __launch_bounds__(256) void k_finalize(const int* __restrict__ bucket_ptr,
                                                  const int* __restrict__ packed,
                                                  int* __restrict__ row_ptr,
                                                  int* __restrict__ col_src) {
    __shared__ int hist[128], part[128], cur[128];
    int b = blockIdx.x, t = threadIdx.x;
    if (t < 128) hist[t] = 0;
    __syncthreads();
    int ebeg = bucket_ptr[b], eend = bucket_ptr[b + 1];
    int m = eend - ebeg;
    for (int i = t; i < m; i += 256)
        atomicAdd(&hist[packed[ebeg + i] & 127], 1);
    __syncthreads();
    int v = 0;
    if (t < 128) { v = hist[t]; part[t] = v; }
    __syncthreads();
    for (int off = 1; off < 128; off <<= 1) {
        int x = 0;
        if (t < 128 && t >= off) x = part[t - off];
        __syncthreads();
        if (t < 128) part[t] += x;
        __syncthreads();
    }
    if (t < 128) {
        int excl = part[t] - v;
        int node = b * 128 + t;
        if (node < N_NODES) row_ptr[node] = ebeg + excl;
        if (node == N_NODES - 1) row_ptr[N_NODES] = eend;
        cur[t] = ebeg + excl;
    }
    __syncthreads();
    for (int i = t; i < m; i += 256) {
        int p = packed[ebeg + i];
        int pos = atomicAdd(&cur[p & 127], 1);
        col_src[pos] = p >> 7;
    }
}

// ================= proj: bf16 MFMA GEMM, head-major epilogue ================
// Qh[head][node][16] fp32; KV[head][node][32] bf16 (K dims 0-15, V dims 16-31).

__global__ __launch_bounds__(256) void proj_mfma(
    const float* __restrict__ h, const unsigned short* __restrict__ Wf,
    const float* __restrict__ bQ, const float* __restrict__ bK, const float* __restrict__ bV,
    float* __restrict__ Qh, unsigned short* __restrict__ KV) {
    int t = threadIdx.x;
    int w = t >> 6;          // wave 0..3
    int l = t & 63;          // lane
    int row0 = blockIdx.x * 64 + w * 16;
    int arow = row0 + (l & 15);
    int akoff = (l >> 4) * 8;
    bool rowok = arow < N_NODES;

    short8 a[4];
#pragma unroll
    for (int ks = 0; ks < 4; ++ks) {
        unsigned short r[8];
        if (rowok) {
            const float4* ap = (const float4*)(h + (size_t)arow * HD + ks * 32 + akoff);
            float4 f0 = ap[0], f1 = ap[1];
            r[0] = f2bf(f0.x); r[1] = f2bf(f0.y); r[2] = f2bf(f0.z); r[3] = f2bf(f0.w);
            r[4] = f2bf(f1.x); r[5] = f2bf(f1.y); r[6] = f2bf(f1.z); r[7] = f2bf(f1.w);
        } else {
#pragma unroll
            for (int j = 0; j < 8; ++j) r[j] = 0;
        }
        a[ks] = *(short8*)r;
    }

    int orow0 = row0 + (l >> 4) * 4;   // output rows orow0..orow0+3
#pragma unroll
    for (int nt = 0; nt < 24; ++nt) {
        floatx4 acc = (floatx4){0.f, 0.f, 0.f, 0.f};
#pragma unroll
        for (int ks = 0; ks < 4; ++ks) {
            U4S8 u;
            u.u = *(const uint4*)(Wf + ((size_t)(nt * 4 + ks) * 64 + l) * 8);
            acc = __builtin_amdgcn_mfma_f32_16x16x32_bf16(a[ks], u.s, acc, 0, 0, 0);
        }
        int g = nt >> 3;
        int head = nt & 7;
        int ci = l & 15;
        float bias = (g == 0) ? bQ[head * 16 + ci] : (g == 1) ? bK[head * 16 + ci] : bV[head * 16 + ci];
#pragma unroll
        for (int r = 0; r < 4; ++r) {
            int grow = orow0 + r;
            if (grow < N_NODES) {
                float val = acc[r] + bias;
                size_t node_off = (size_t)head * N_PAD + grow;
                if (g == 0)      Qh[node_off * 16 + ci] = val;
                else if (g == 1) KV[node_off * 32 + ci] = f2bf(val);
                else             KV[node_off * 32 + 16 + ci] = f2bf(val);
            }
        }
    }
}

// ================= attention: head-split + full-edge-per-lane ===============
// blockIdx = grp*8 + head (head -> XCD pinned; per-XCD KV slice 3.2 MB in L2).
// Block 256 = 4 waves; wave = 8 nodes x 8 edge slots. Lane = one full
// edge-head: loads 64B KV row, in-lane 16-FMA dot + 16-FMA acc, one exp.
// Divergent per-lane edge loop (exec mask = validity). 2-deep KV pipeline.

__device__ __forceinline__ float blo(unsigned u) { return __uint_as_float(u << 16); }
__device__ __forceinline__ float bhi(unsigned u) { return __uint_as_float(u & 0xffff0000u); }

__global__ __launch_bounds__(256) void attn_kernel(
    const float* __restrict__ Qh, const unsigned short* __restrict__ KV,
    const int* __restrict__ row_ptr, const int* __restrict__ col_src,
    float* __restrict__ out) {
    int head = blockIdx.x & 7;
    int grp  = blockIdx.x >> 3;
    int w = threadIdx.x >> 6;
    int l = threadIdx.x & 63;
    int q = l >> 3;          // node sub-index 0..7
    int s = l & 7;           // edge slot 0..7
    int n = grp * 32 + w * 8 + q;
    bool nok = n < N_NODES;

    const float4* qp = (const float4*)(Qh + ((size_t)head * N_PAD + n) * 16);
    float4 q0 = qp[0], q1 = qp[1], q2 = qp[2], q3 = qp[3];

    float acc[16];
#pragma unroll
    for (int j = 0; j < 16; ++j) acc[j] = 0.f;
    float z = 0.f;

    int beg = 0, end = 0;
    if (nok) { beg = row_ptr[n]; end = row_ptr[n + 1]; }
    const unsigned short* KVh = KV + (size_t)head * N_PAD * 32;

    int e = beg + s;
    int idx0 = col_src[(e < end) ? e : beg];
    const uint4* rp = (const uint4*)(KVh + (size_t)idx0 * 32);
    uint4 c0 = rp[0], c1 = rp[1], c2 = rp[2], c3 = rp[3];

    while (e < end) {
        int e2 = e + 8;
        int idxn = col_src[(e2 < end) ? e2 : beg];
        const uint4* np = (const uint4*)(KVh + (size_t)idxn * 32);
        uint4 n0 = np[0], n1 = np[1], n2 = np[2], n3 = np[3];

        float dot = blo(c0.x) * q0.x + bhi(c0.x) * q0.y
                  + blo(c0.y) * q0.z + bhi(c0.y) * q0.w
                  + blo(c0.z) * q1.x + bhi(c0.z) * q1.y
                  + blo(c0.w) * q1.z + bhi(c0.w) * q1.w
                  + blo(c1.x) * q2.x + bhi(c1.x) * q2.y
                  + blo(c1.y) * q2.z + bhi(c1.y) * q2.w
                  + blo(c1.z) * q3.x + bhi(c1.z) * q3.y
                  + blo(c1.w) * q3.z + bhi(c1.w) * q3.w;
        float sc = __expf(fminf(fmaxf(dot * 0.25f, -5.f), 5.f));
        acc[0]  = fmaf(sc, blo(c2.x), acc[0]);
        acc[1]  = fmaf(sc, bhi(c2.x), acc[1]);
        acc[2]  = fmaf(sc, blo(c2.y), acc[2]);
        acc[3]  = fmaf(sc, bhi(c2.y), acc[3]);
        acc[4]  = fmaf(sc, blo(c2.z), acc[4]);
        acc[5]  = fmaf(sc, bhi(c2.z), acc[5]);
        acc[6]  = fmaf(sc, blo(c2.w), acc[6]);
        acc[7]  = fmaf(sc, bhi(c2.w), acc[7]);
        acc[8]  = fmaf(sc, blo(c3.x), acc[8]);
        acc[9]  = fmaf(sc, bhi(c3.x), acc[9]);
        acc[10] = fmaf(sc, blo(c3.y), acc[10]);
        acc[11] = fmaf(sc, bhi(c3.y), acc[11]);
        acc[12] = fmaf(sc, blo(c3.z), acc[12]);
        acc[13] = fmaf(sc, bhi(c3.z), acc[13]);
        acc[14] = fmaf(sc, blo(c3.w), acc[14]);
        acc[15] = fmaf(sc, bhi(c3.w), acc[15]);
        z += sc;
        c0 = n0; c1 = n1; c2 = n2; c3 = n3;
        e = e2;
    }

    // reduce across 8 edge slots (xor 1,2,4)
#pragma unroll
    for (int j = 0; j < 16; ++j) {
        acc[j] += __shfl_xor(acc[j], 1);
        acc[j] += __shfl_xor(acc[j], 2);
        acc[j] += __shfl_xor(acc[j], 4);
    }
    z += __shfl_xor(z, 1);
    z += __shfl_xor(z, 2);
    z += __shfl_xor(z, 4);

    if (s == 0 && nok) {
        float inv = 1.f / z;
        float* O = out + (size_t)n * HD + head * 16;
        ((float4*)O)[0] = (float4){acc[0] * inv,  acc[1] * inv,  acc[2] * inv,  acc[3] * inv};
        ((float4*)O)[1] = (float4){acc[4] * inv,  acc[5] * inv,  acc[6] * inv,  acc[7] * inv};
        ((float4*)O)[2] = (float4){acc[8] * inv,  acc[9] * inv,  acc[10] * inv, acc[11] * inv};
        ((float4*)O)[3] = (float4){acc[12] * inv, acc[13] * inv, acc[14] * inv, acc[15] * inv};
    }
}

// ================= launch ===================================================

static inline char* align256(char* p) {
    return (char*)(((uintptr_t)p + 255) & ~(uintptr_t)255);
}

extern "C" void kernel_launch(void* const* d_in, const int* in_sizes, int n_in,
                              void* d_out, int out_size, void* d_ws, size_t ws_size,
                              hipStream_t stream) {
    const float* h  = (const float*)d_in[0];
    const int*   src = (const int*)d_in[1];
    const int*   dst = (const int*)d_in[2];
    const float* WQ = (const float*)d_in[3];
    const float* WK = (const float*)d_in[4];
    const float* WV = (const float*)d_in[5];
    const float* bQ = (const float*)d_in[6];
    const float* bK = (const float*)d_in[7];
    const float* bV = (const float*)d_in[8];
    float* out = (float*)d_out;

    char* p = (char*)d_ws;
    float* Qh = (float*)p;                   p += (size_t)8 * N_PAD * 16 * 4;
    unsigned short* KV = (unsigned short*)p; p += (size_t)8 * N_PAD * 32 * 2;
    unsigned short* Wf = (unsigned short*)p; p += (size_t)24 * 4 * 64 * 8 * 2;
    p = align256(p);
    int* row_ptr    = (int*)p;               p += (N_NODES + 2) * 4;
    p = align256(p);
    int* bucket_ptr = (int*)p;               p += (NBUCKET + 1) * 4;
    p = align256(p);
    int* btot       = (int*)p;               p += NBUCKET * 4;
    p = align256(p);
    int* chunkhist  = (int*)p;               p += (size_t)NCHUNK * NBUCKET * 4;
    p = align256(p);
    int* chunkoff   = (int*)p;               p += (size_t)NCHUNK * NBUCKET * 4;
    p = align256(p);
    int* packed     = (int*)p;               p += (size_t)N_EDGES * 4;
    p = align256(p);
    int* col_src    = (int*)p;               p += (size_t)N_EDGES * 4;

    (void)hipMemsetAsync(btot, 0, NBUCKET * sizeof(int), stream);
    k_chunkhist<<<NCHUNK + 24, 256, 0, stream>>>(dst, chunkhist, btot, WQ, WK, WV, Wf);
    k_choff<<<NBUCKET, 256, 0, stream>>>(chunkhist, btot, bucket_ptr, chunkoff);
    k_scatter<<<NCHUNK, 256, 0, stream>>>(src, dst, chunkoff, packed);
    k_finalize<<<NBUCKET, 256, 0, stream>>>(bucket_ptr, packed, row_ptr, col_src);
    proj_mfma<<<N_PAD / 64, 256, 0, stream>>>(h, Wf, bQ, bK, bV, Qh, KV);
    int grps = (N_NODES + 31) / 32;          // 1563
    attn_kernel<<<grps * 8, 256, 0, stream>>>(Qh, KV, row_ptr, col_src, out);
}